// Round 1
// baseline (45150.470 us; speedup 1.0000x reference)
//
#include <hip/hip_runtime.h>
#include <cstddef>

// SparseRNN: dilated RNN, 512 sequential steps.
// Per-step kernel pipeline (depth 3): kernel t computes
//   L1  : pre1[t]   += [emb(x[:,t]) | z1 hist o=256..1] @ W1   (atomic K-split)
//   L2  : pre2[t-1] += [z1[t-1]     | z2 hist o=256..1] @ W2
//   ACT1: z1act[t-1] = tanh(pre1[t-1]+b1)   ACT2: z2act[t-2] = tanh(pre2[t-2]+b2)
//   O   : out[:,t-3,:] = z2act[t-3] @ Wo + bo
//   Z   : zero pre ring slot (t+4)%8 for reuse
// Offset-1 chunks (and L2's z1 input) read the pre ring + tanh-on-read since the
// activated ring for that step is finalized in the same kernel.

namespace {
constexpr int BB = 64;     // batch
constexpr int SS = 512;    // seq len
constexpr int HH = 512;    // hidden = emb dim
constexpr int NCL = 1000;  // classes
constexpr int RP = 8;      // pre-activation ring slots
constexpr int RA = 260;    // activation ring slots (> 256 offsets, no aliasing)
constexpr int KC = 128;    // K chunk per gemm block
constexpr int NT = 16;     // n tile (L1/L2)
constexpr int NTO = 8;     // n tile (out)
constexpr int NB1 = HH / NT;          // 32 n-blocks
constexpr int L1B = 10 * 4 * NB1;     // 40 K-chunks x 32 = 1280
constexpr int L2B = L1B;
constexpr int OB = NCL / NTO;         // 125
constexpr int AB = 16;                // act blocks per layer
constexpr int ZB = 8;
constexpr int GRID = L1B + L2B + OB + 2 * AB + ZB;  // 2725
constexpr int SLOT = BB * HH;         // 32768 floats per time slot
}

__device__ __forceinline__ float tanh_f(float x) {
  x = fminf(15.f, fmaxf(-15.f, x));
  float e = __expf(2.f * x);
  return __fdividef(e - 1.f, e + 1.f);
}

__global__ __launch_bounds__(64) void sparse_rnn_step(
    int t,
    const int* __restrict__ x, const float* __restrict__ emb,
    const float* __restrict__ W1, const float* __restrict__ b1,
    const float* __restrict__ W2, const float* __restrict__ b2,
    const float* __restrict__ Wo, const float* __restrict__ bo,
    float* __restrict__ out,
    float* __restrict__ pre1, float* __restrict__ pre2,
    float* __restrict__ z1a, float* __restrict__ z2a)
{
  __shared__ float lds[64 * 65];  // A tile, transposed [k][m], stride 65
  int bid = blockIdx.x;
  const int tid = threadIdx.x;

  if (bid < L1B + L2B) {
    // ---- L1 / L2 GEMM chunk block ----
    const int layer = (bid >= L1B) ? 1 : 0;
    const int lb = layer ? bid - L1B : bid;
    const int kcid = lb / NB1;          // 0..39
    const int nb = lb - kcid * NB1;     // 0..31
    const int u = t - layer;            // time being computed
    if (u < 0 || u >= SS) return;
    const int sb = kcid >> 2;           // source block 0..9
    const int koff = (kcid & 3) * KC;   // col offset within source block
    const float* __restrict__ W = layer ? W2 : W1;
    const float* src = nullptr;
    const float* bias = nullptr;
    int mode;  // 0: emb gather, 1: activated ring, 2: pre ring + tanh
    if (sb == 0) {
      if (!layer) {
        mode = 0;
      } else {
        mode = 2; src = pre1 + (size_t)(u % RP) * SLOT; bias = b1;
      }
    } else {
      const int o = 1 << (9 - sb);      // offset 256..1
      if (o > u) return;                // invalid -> zero contribution
      if (o == 1) {
        mode = 2;
        src = (layer ? pre2 : pre1) + (size_t)((u - 1) % RP) * SLOT;
        bias = layer ? b2 : b1;
      } else {
        mode = 1;
        src = (layer ? z2a : z1a) + (size_t)((u - o) % RA) * SLOT;
      }
    }
    const int n0 = nb * NT;
    const int mt = tid & 15;
    const int nt = tid >> 4;            // 0..3
    const int lrow = tid >> 4;          // staging row-in-quad
    const int lc4 = (tid & 15) * 4;     // staging col*4
    float acc[4][4] = {};
    for (int sc = 0; sc < KC; sc += 64) {
      const int kb = koff + sc;
#pragma unroll
      for (int q = 0; q < 16; q++) {
        const int m = q * 4 + lrow;
        float4 v;
        if (mode == 0) {
          const int xi = x[m * SS + t];
          v = *(const float4*)(emb + (size_t)xi * HH + kb + lc4);
        } else {
          v = *(const float4*)(src + (size_t)m * HH + kb + lc4);
        }
        if (mode == 2) {
          v.x = tanh_f(v.x + bias[kb + lc4 + 0]);
          v.y = tanh_f(v.y + bias[kb + lc4 + 1]);
          v.z = tanh_f(v.z + bias[kb + lc4 + 2]);
          v.w = tanh_f(v.w + bias[kb + lc4 + 3]);
        }
        lds[(lc4 + 0) * 65 + m] = v.x;
        lds[(lc4 + 1) * 65 + m] = v.y;
        lds[(lc4 + 2) * 65 + m] = v.z;
        lds[(lc4 + 3) * 65 + m] = v.w;
      }
      __syncthreads();
      const float* __restrict__ Wp = W + (size_t)(sb * HH + kb) * HH + n0 + 4 * nt;
#pragma unroll 4
      for (int k = 0; k < 64; k++) {
        float a[4];
        a[0] = lds[k * 65 + 4 * mt + 0];
        a[1] = lds[k * 65 + 4 * mt + 1];
        a[2] = lds[k * 65 + 4 * mt + 2];
        a[3] = lds[k * 65 + 4 * mt + 3];
        const float4 w = *(const float4*)(Wp + (size_t)k * HH);
#pragma unroll
        for (int i = 0; i < 4; i++) {
          acc[i][0] = fmaf(a[i], w.x, acc[i][0]);
          acc[i][1] = fmaf(a[i], w.y, acc[i][1]);
          acc[i][2] = fmaf(a[i], w.z, acc[i][2]);
          acc[i][3] = fmaf(a[i], w.w, acc[i][3]);
        }
      }
      __syncthreads();
    }
    float* dst = (layer ? pre2 : pre1) + (size_t)(u % RP) * SLOT;
#pragma unroll
    for (int i = 0; i < 4; i++)
#pragma unroll
      for (int j = 0; j < 4; j++)
        atomicAdd(dst + (4 * mt + i) * HH + n0 + 4 * nt + j, acc[i][j]);
    return;
  }
  bid -= L1B + L2B;

  if (bid < OB) {
    // ---- output GEMM block: pred[t-3] ----
    const int v = t - 3;
    if (v < 0 || v >= SS) return;
    const float* src = z2a + (size_t)(v % RA) * SLOT;
    const int n0 = bid * NTO;
    const int mt = tid & 15;
    const int nt = tid >> 4;            // 0..3
    const int lrow = tid >> 4;
    const int lc4 = (tid & 15) * 4;
    float acc[4][2] = {};
    for (int sc = 0; sc < HH; sc += 64) {
#pragma unroll
      for (int q = 0; q < 16; q++) {
        const int m = q * 4 + lrow;
        const float4 vv = *(const float4*)(src + (size_t)m * HH + sc + lc4);
        lds[(lc4 + 0) * 65 + m] = vv.x;
        lds[(lc4 + 1) * 65 + m] = vv.y;
        lds[(lc4 + 2) * 65 + m] = vv.z;
        lds[(lc4 + 3) * 65 + m] = vv.w;
      }
      __syncthreads();
      const float* __restrict__ Wp = Wo + (size_t)sc * NCL + n0 + 2 * nt;
#pragma unroll 4
      for (int k = 0; k < 64; k++) {
        float a[4];
        a[0] = lds[k * 65 + 4 * mt + 0];
        a[1] = lds[k * 65 + 4 * mt + 1];
        a[2] = lds[k * 65 + 4 * mt + 2];
        a[3] = lds[k * 65 + 4 * mt + 3];
        const float2 w = *(const float2*)(Wp + (size_t)k * NCL);
#pragma unroll
        for (int i = 0; i < 4; i++) {
          acc[i][0] = fmaf(a[i], w.x, acc[i][0]);
          acc[i][1] = fmaf(a[i], w.y, acc[i][1]);
        }
      }
      __syncthreads();
    }
#pragma unroll
    for (int i = 0; i < 4; i++) {
      const int m = 4 * mt + i;
      const int n = n0 + 2 * nt;
      out[(size_t)m * (SS * NCL) + (size_t)v * NCL + n]     = acc[i][0] + bo[n];
      out[(size_t)m * (SS * NCL) + (size_t)v * NCL + n + 1] = acc[i][1] + bo[n + 1];
    }
    return;
  }
  bid -= OB;

  if (bid < 2 * AB) {
    // ---- activation finalize ----
    const int layer = (bid >= AB) ? 1 : 0;
    const int ab = layer ? bid - AB : bid;
    const int u = t - 1 - layer;
    if (u < 0 || u >= SS) return;
    const float* p = (layer ? pre2 : pre1) + (size_t)(u % RP) * SLOT;
    const float* bias = layer ? b2 : b1;
    float* za = (layer ? z2a : z1a) + (size_t)(u % RA) * SLOT;
    for (int it = 0; it < 32; it++) {
      const int idx = ab * 2048 + it * 64 + tid;
      za[idx] = tanh_f(p[idx] + bias[idx & (HH - 1)]);
    }
    return;
  }
  bid -= 2 * AB;

  {
    // ---- zero pre ring slot (t+4)%RP for both layers ----
    const int slot = (t + 4) % RP;
    float* p1 = pre1 + (size_t)slot * SLOT;
    float* p2 = pre2 + (size_t)slot * SLOT;
    for (int it = 0; it < 64; it++) {
      const int idx = bid * 4096 + it * 64 + tid;
      p1[idx] = 0.f;
      p2[idx] = 0.f;
    }
  }
}

__global__ void zero_ws(float* __restrict__ p, int n) {
  const int i = blockIdx.x * blockDim.x + threadIdx.x;
  if (i < n) p[i] = 0.f;
}

extern "C" void kernel_launch(void* const* d_in, const int* in_sizes, int n_in,
                              void* d_out, int out_size, void* d_ws, size_t ws_size,
                              hipStream_t stream) {
  const int*   x   = (const int*)d_in[0];
  const float* emb = (const float*)d_in[1];
  const float* W1  = (const float*)d_in[2];
  const float* b1  = (const float*)d_in[3];
  const float* W2  = (const float*)d_in[4];
  const float* b2  = (const float*)d_in[5];
  const float* Wo  = (const float*)d_in[6];
  const float* bo  = (const float*)d_in[7];
  float* out = (float*)d_out;

  // ws layout (floats): pre1[8][64][512] | pre2[8][64][512] |
  //                     z1act[260][64][512] | z2act[260][64][512]  = 70.3 MB
  float* pre1 = (float*)d_ws;
  float* pre2 = pre1 + (size_t)RP * SLOT;
  float* z1a  = pre2 + (size_t)RP * SLOT;
  float* z2a  = z1a + (size_t)RA * SLOT;

  const int nz = 2 * RP * SLOT;  // zero pre rings (ws is poisoned 0xAA)
  zero_ws<<<(nz + 255) / 256, 256, 0, stream>>>(pre1, nz);

  for (int t = 0; t < SS + 3; t++) {
    sparse_rnn_step<<<GRID, 64, 0, stream>>>(t, x, emb, W1, b1, W2, b2, Wo, bo,
                                             out, pre1, pre2, z1a, z2a);
  }
}

// Round 2
// 28932.257 us; speedup vs baseline: 1.5606x; 1.5606x over previous
//
#include <hip/hip_runtime.h>
#include <cstddef>

// SparseRNN dilated RNN, 512 sequential steps. Two kernels per step, NO atomics:
//  A(t): K-split GEMM blocks write partial pre-activation tiles (plain stores):
//        L1 partials for step t   : [emb(x[:,t]) | z1a(t-256..t-1)] @ W1-chunks
//        L2 partials for step t-1 : [z1a(t-1)    | z2a(t-257..t-2)] @ W2-chunks
//        OUT for step t-2         : z2a(t-2) @ Wo + bo  -> d_out
//  B(t): reduce 40 partials/layer (+bias, tanh) -> z1a[t], z2a[t-1] rings.
//        Offset validity (o<=u) handled by skipping unwritten partials.
// No atomics: the R1 version's 2.6M device-scope atomicAdd/step (~166MB/step of
// fabric RMW at line granularity) is the 88us/step theory being tested.

namespace {
constexpr int BB  = 64;    // batch
constexpr int SS  = 512;   // seq len
constexpr int HH  = 512;   // hidden = emb dim
constexpr int NCL = 1000;  // classes
constexpr int RA  = 260;   // activation ring slots (>257 => no aliasing)
constexpr int SLOT = BB * HH;        // 32768 floats per time slot
constexpr int NKC = 40;              // K-chunks of 128 per layer (K=5120)
constexpr int GEMMB = NKC * 16;      // 640 blocks/layer (16 n-tiles of 32)
constexpr int OUTB  = 126;           // 63 n-tiles of 16 x 2 m-halves
constexpr int GRIDA = 2 * GEMMB + OUTB;  // 1406
constexpr int GRIDB = 128;           // 64 blocks/layer reduce
constexpr int LDST  = 66;            // LDS stride: b64-aligned reads, low conflict
}

__device__ __forceinline__ float tanh_f(float x) {
  x = fminf(15.f, fmaxf(-15.f, x));
  float e = __expf(2.f * x);
  return __fdividef(e - 1.f, e + 1.f);
}

__global__ __launch_bounds__(128) void rnn_gemm(
    int t,
    const int* __restrict__ x, const float* __restrict__ emb,
    const float* __restrict__ W1, const float* __restrict__ W2,
    const float* __restrict__ Wo, const float* __restrict__ bo,
    const float* __restrict__ z1a, const float* __restrict__ z2a,
    float* __restrict__ pre1p, float* __restrict__ pre2p,
    float* __restrict__ out)
{
  __shared__ float lds[64 * LDST];  // A tile transposed [k][m]
  int bid = blockIdx.x;
  const int tid = threadIdx.x;

  if (bid < 2 * GEMMB) {
    // ---- L1/L2 K-split GEMM: 64m x 32n tile, K-chunk 128 ----
    const int layer = (bid >= GEMMB) ? 1 : 0;
    const int lb = bid - layer * GEMMB;
    const int kcid = lb >> 4;          // 0..39
    const int nb = lb & 15;            // 0..15
    const int u = t - layer;           // step being computed
    if (u < 0 || u >= SS) return;
    const int sb = kcid >> 2;          // source block 0..9
    const int koff = (kcid & 3) * 128; // col offset in source block
    const float* __restrict__ W = layer ? W2 : W1;
    const float* src = nullptr;
    bool embmode = false;
    if (sb == 0) {
      if (!layer) embmode = true;               // emb gather
      else        src = z1a + (size_t)(u % RA) * SLOT;  // z1[t-1] activated
    } else {
      const int o = 1 << (9 - sb);     // offset 256..1
      if (o > u) return;               // invalid -> partial skipped by reducer
      src = (layer ? z2a : z1a) + (size_t)((u - o) % RA) * SLOT;
    }
    const int n0 = nb * 32;
    const int mt = tid & 15;           // 4 m-rows each
    const int nt = tid >> 4;           // 0..7, 4 n-cols each
    const int srow = tid >> 4;         // staging row 0..7
    const int sc4 = (tid & 15) * 4;    // staging col*4
    float acc[4][4] = {};
    for (int sc = 0; sc < 128; sc += 64) {
#pragma unroll
      for (int q = 0; q < 8; q++) {
        const int m = q * 8 + srow;
        const int col = koff + sc + sc4;
        float4 v;
        if (embmode) {
          const int xi = x[m * SS + t];
          v = *(const float4*)(emb + (size_t)xi * HH + col);
        } else {
          v = *(const float4*)(src + (size_t)m * HH + col);
        }
        lds[(sc4 + 0) * LDST + m] = v.x;
        lds[(sc4 + 1) * LDST + m] = v.y;
        lds[(sc4 + 2) * LDST + m] = v.z;
        lds[(sc4 + 3) * LDST + m] = v.w;
      }
      __syncthreads();
      const float* __restrict__ Wp =
          W + (size_t)(sb * HH + koff + sc) * HH + n0 + 4 * nt;
#pragma unroll 4
      for (int k = 0; k < 64; k++) {
        float a0 = lds[k * LDST + 4 * mt + 0];
        float a1 = lds[k * LDST + 4 * mt + 1];
        float a2 = lds[k * LDST + 4 * mt + 2];
        float a3 = lds[k * LDST + 4 * mt + 3];
        const float4 w = *(const float4*)(Wp + (size_t)k * HH);
        acc[0][0] = fmaf(a0, w.x, acc[0][0]); acc[0][1] = fmaf(a0, w.y, acc[0][1]);
        acc[0][2] = fmaf(a0, w.z, acc[0][2]); acc[0][3] = fmaf(a0, w.w, acc[0][3]);
        acc[1][0] = fmaf(a1, w.x, acc[1][0]); acc[1][1] = fmaf(a1, w.y, acc[1][1]);
        acc[1][2] = fmaf(a1, w.z, acc[1][2]); acc[1][3] = fmaf(a1, w.w, acc[1][3]);
        acc[2][0] = fmaf(a2, w.x, acc[2][0]); acc[2][1] = fmaf(a2, w.y, acc[2][1]);
        acc[2][2] = fmaf(a2, w.z, acc[2][2]); acc[2][3] = fmaf(a2, w.w, acc[2][3]);
        acc[3][0] = fmaf(a3, w.x, acc[3][0]); acc[3][1] = fmaf(a3, w.y, acc[3][1]);
        acc[3][2] = fmaf(a3, w.z, acc[3][2]); acc[3][3] = fmaf(a3, w.w, acc[3][3]);
      }
      __syncthreads();
    }
    float* pp = (layer ? pre2p : pre1p) + (size_t)kcid * SLOT;
#pragma unroll
    for (int i = 0; i < 4; i++) {
      float4 st = make_float4(acc[i][0], acc[i][1], acc[i][2], acc[i][3]);
      *(float4*)(pp + (size_t)(4 * mt + i) * HH + n0 + 4 * nt) = st;
    }
    return;
  }
  bid -= 2 * GEMMB;

  // ---- OUT GEMM: out[:, t-2, :] = z2a[t-2] @ Wo + bo ; 32m x 16n, K=512 ----
  {
    const int v = t - 2;
    if (v < 0 || v >= SS) return;
    const int nb = bid >> 1;
    const int mh = bid & 1;
    const int n0 = nb * 16;
    const float* src = z2a + (size_t)(v % RA) * SLOT;
    const int mt = tid & 7;            // 4 rows each (32 rows)
    const int nt = tid >> 3;           // 0..15, 1 col each
    const int srow = tid >> 4;         // 0..7
    const int sc4 = (tid & 15) * 4;
    const int n = n0 + nt;
    const int nn = (n < NCL) ? n : (NCL - 1);  // clamp loads for last tile
    float acc[4] = {};
    for (int sc = 0; sc < HH; sc += 64) {
#pragma unroll
      for (int q = 0; q < 4; q++) {
        const int m = q * 8 + srow;    // local 0..31
        const float4 vv =
            *(const float4*)(src + (size_t)(mh * 32 + m) * HH + sc + sc4);
        lds[(sc4 + 0) * LDST + m] = vv.x;
        lds[(sc4 + 1) * LDST + m] = vv.y;
        lds[(sc4 + 2) * LDST + m] = vv.z;
        lds[(sc4 + 3) * LDST + m] = vv.w;
      }
      __syncthreads();
#pragma unroll 4
      for (int k = 0; k < 64; k++) {
        const float w = Wo[(size_t)(sc + k) * NCL + nn];
        acc[0] = fmaf(lds[k * LDST + 4 * mt + 0], w, acc[0]);
        acc[1] = fmaf(lds[k * LDST + 4 * mt + 1], w, acc[1]);
        acc[2] = fmaf(lds[k * LDST + 4 * mt + 2], w, acc[2]);
        acc[3] = fmaf(lds[k * LDST + 4 * mt + 3], w, acc[3]);
      }
      __syncthreads();
    }
    if (n < NCL) {
#pragma unroll
      for (int i = 0; i < 4; i++) {
        const int m = mh * 32 + 4 * mt + i;
        out[(size_t)m * (SS * NCL) + (size_t)v * NCL + n] = acc[i] + bo[n];
      }
    }
  }
}

__global__ __launch_bounds__(128) void rnn_reduce(
    int t,
    const float* __restrict__ b1, const float* __restrict__ b2,
    const float* __restrict__ pre1p, const float* __restrict__ pre2p,
    float* __restrict__ z1a, float* __restrict__ z2a)
{
  const int blk = blockIdx.x;
  const int layer = (blk >= 64) ? 1 : 0;
  const int u = t - layer;
  if (u < 0 || u >= SS) return;
  const float* __restrict__ pp = layer ? pre2p : pre1p;
  const float* __restrict__ bias = layer ? b2 : b1;
  float* za = (layer ? z2a : z1a) + (size_t)(u % RA) * SLOT;
  const int e4 = ((blk & 63) * 128 + (int)threadIdx.x) * 4;
  float sx = 0.f, sy = 0.f, sz = 0.f, sw = 0.f;
  for (int sb = 0; sb < 10; sb++) {
    if (sb > 0) {
      const int o = 1 << (9 - sb);
      if (o > u) continue;  // invalid offset: partial never written
    }
#pragma unroll
    for (int ks = 0; ks < 4; ks++) {
      const float4 p = *(const float4*)(pp + (size_t)(sb * 4 + ks) * SLOT + e4);
      sx += p.x; sy += p.y; sz += p.z; sw += p.w;
    }
  }
  const int bc = e4 & (HH - 1);
  float4 r;
  r.x = tanh_f(sx + bias[bc + 0]);
  r.y = tanh_f(sy + bias[bc + 1]);
  r.z = tanh_f(sz + bias[bc + 2]);
  r.w = tanh_f(sw + bias[bc + 3]);
  *(float4*)(za + e4) = r;
}

extern "C" void kernel_launch(void* const* d_in, const int* in_sizes, int n_in,
                              void* d_out, int out_size, void* d_ws, size_t ws_size,
                              hipStream_t stream) {
  const int*   x   = (const int*)d_in[0];
  const float* emb = (const float*)d_in[1];
  const float* W1  = (const float*)d_in[2];
  const float* b1  = (const float*)d_in[3];
  const float* W2  = (const float*)d_in[4];
  const float* b2  = (const float*)d_in[5];
  const float* Wo  = (const float*)d_in[6];
  const float* bo  = (const float*)d_in[7];
  float* out = (float*)d_out;

  // ws (floats): pre1p[40][64][512] | pre2p[40][64][512] |
  //              z1a[260][64][512]  | z2a[260][64][512]   = 78.6 MB
  float* pre1p = (float*)d_ws;
  float* pre2p = pre1p + (size_t)NKC * SLOT;
  float* z1a   = pre2p + (size_t)NKC * SLOT;
  float* z2a   = z1a + (size_t)RA * SLOT;

  for (int t = 0; t < SS + 2; t++) {
    rnn_gemm<<<GRIDA, 128, 0, stream>>>(t, x, emb, W1, W2, Wo, bo,
                                        z1a, z2a, pre1p, pre2p, out);
    if (t <= SS)
      rnn_reduce<<<GRIDB, 128, 0, stream>>>(t, b1, b2, pre1p, pre2p, z1a, z2a);
  }
}